// Round 5
// baseline (1169.013 us; speedup 1.0000x reference)
//
#include <hip/hip_runtime.h>
#include <hip/hip_bf16.h>
#include <math.h>

// Problem constants (fixed by the reference)
#define B_ROWS 16384
#define D_DIM  4096
#define H_DIM  2048
#define E_DIM  64
#define TEMP   0.8f

typedef __bf16 bf16x8 __attribute__((ext_vector_type(8)));
typedef float  f32x4  __attribute__((ext_vector_type(4)));
typedef unsigned short ushort8 __attribute__((ext_vector_type(8)));

__device__ __forceinline__ unsigned short bf_rne(float f) {
  unsigned u = __float_as_uint(f);
  u += 0x7FFF + ((u >> 16) & 1);
  return (unsigned short)(u >> 16);
}

__device__ __forceinline__ void async_copy16(const void* g, void* l) {
  __builtin_amdgcn_global_load_lds(
      (const __attribute__((address_space(1))) void*)g,
      (__attribute__((address_space(3))) void*)l, 16, 0, 0);
}

// ---------------------------------------------------------------------------
// split: fp32 -> (hi bf16, lo bf16), RNE both. 8 elements / thread.
// ---------------------------------------------------------------------------
__global__ __launch_bounds__(256) void split_kernel(
    const float* __restrict__ in, unsigned short* __restrict__ hi,
    unsigned short* __restrict__ lo) {
  const size_t i = ((size_t)blockIdx.x * 256 + threadIdx.x) * 8;
  float4 v0 = *(const float4*)(in + i);
  float4 v1 = *(const float4*)(in + i + 4);
  float f[8] = {v0.x, v0.y, v0.z, v0.w, v1.x, v1.y, v1.z, v1.w};
  ushort8 hv, lv;
#pragma unroll
  for (int j = 0; j < 8; ++j) {
    unsigned short h = bf_rne(f[j]);
    float fh = __uint_as_float(((unsigned)h) << 16);
    hv[j] = h;
    lv[j] = bf_rne(f[j] - fh);
  }
  *(ushort8*)(hi + i) = hv;
  *(ushort8*)(lo + i) = lv;
}

// ---------------------------------------------------------------------------
// K1 v6: 256x256 tile, BK=32, 8 waves, 8-phase counted-vmcnt schedule,
// XCD-slab mapping + register hoisting + NEW: prefetch-shifted fragment
// reads. The ds_reads for phase p+1 are issued INSIDE phase p's MFMA window,
// so the LDS pipe (avg ~384-768 cy/phase) overlaps the matrix pipe (774 cy)
// instead of alternating with it (R4 model: 768+774+overhead = 1585 cy/phase
// measured). q3's vmcnt(4) moves BEFORE its prefetch reads (strictly
// tighter), gating the next-buffer reads exactly as before.
// Ledger re-verified: every prefetch read is >=3 barriers before the stage
// that overwrites its region; every next-buf read is after the vmcnt that
// covers its 8 staging loads (prologue included). Same MFMA order ->
// bit-identical numerics.
// ---------------------------------------------------------------------------
#define G_BM 256
#define G_BN 256
#define G_BK 32
#define G_NT (D_DIM / G_BK)   // 128 K-tiles, 64 iters

#define MFMA_TRIPLE(MIv, NIv, FAH, FAL, FBH, FBL)                               \
  _Pragma("unroll")                                                             \
  for (int mf = 0; mf < 4; ++mf) {                                              \
    _Pragma("unroll")                                                           \
    for (int nf = 0; nf < 2; ++nf) {                                            \
      f32x4 a = acc[MIv][mf][NIv][nf];                                          \
      a = __builtin_amdgcn_mfma_f32_16x16x32_bf16(FAH[mf], FBH[nf], a, 0, 0, 0);\
      a = __builtin_amdgcn_mfma_f32_16x16x32_bf16(FAL[mf], FBH[nf], a, 0, 0, 0);\
      a = __builtin_amdgcn_mfma_f32_16x16x32_bf16(FAH[mf], FBL[nf], a, 0, 0, 0);\
      acc[MIv][mf][NIv][nf] = a;                                                \
    }                                                                           \
  }

__global__ __launch_bounds__(512, 2) void gemm1_8ph_kernel(
    const unsigned short* __restrict__ xh, const unsigned short* __restrict__ xl,
    const unsigned short* __restrict__ w1h, const unsigned short* __restrict__ w1l,
    const float* __restrict__ b1,
    unsigned short* __restrict__ hhp, unsigned short* __restrict__ hlp) {
  __shared__ unsigned short LAh[2 * 8192];   // [buf][256][32] bf16 = 32 KB
  __shared__ unsigned short LAl[2 * 8192];
  __shared__ unsigned short LBh[2 * 8192];
  __shared__ unsigned short LBl[2 * 8192];

  const int t    = threadIdx.x;          // 0..511
  const int lane = t & 63;
  const int w    = t >> 6;               // 0..7
  const int wm   = w >> 2;               // 0..1
  const int wn   = w & 3;                // 0..3

  // XCD-slab swizzle (bijective: 512 wgs = 8 xcds x 8 mt x 8 nt)
  const int wg   = blockIdx.x;
  const int xcd  = wg & 7;
  const int slot = wg >> 3;              // 0..63
  const int mt   = xcd * 8 + (slot >> 3);
  const int nt   = slot & 7;
  const int m0   = mt * G_BM;
  const int n0   = nt * G_BN;

  // ---- staging addresses: 512 threads cover 128 rows x 4 col-chunks ----
  const int sr  = t >> 2;                        // 0..127
  const int sc  = (t & 3) * 8;
  const int scs = sc ^ (((sr >> 1) & 3) << 3);   // pre-swizzled source col
  const int t8  = t * 8;                         // linear dest
  const unsigned short* gAh = xh  + (size_t)(m0 + sr) * D_DIM + scs;
  const unsigned short* gAl = xl  + (size_t)(m0 + sr) * D_DIM + scs;
  const unsigned short* gBh = w1h + (size_t)(n0 + sr) * D_DIM + scs;
  const unsigned short* gBl = w1l + (size_t)(n0 + sr) * D_DIM + scs;

  auto stageA = [&](int buf, int half, int kt) {
    const size_t go = (size_t)half * 128 * D_DIM + (size_t)kt * G_BK;
    const int lo = buf * 8192 + half * 4096 + t8;
    async_copy16(gAh + go, &LAh[lo]);
    async_copy16(gAl + go, &LAl[lo]);
  };
  auto stageB = [&](int buf, int half, int kt) {
    const size_t go = (size_t)half * 128 * D_DIM + (size_t)kt * G_BK;
    const int lo = buf * 8192 + half * 4096 + t8;
    async_copy16(gBh + go, &LBh[lo]);
    async_copy16(gBl + go, &LBl[lo]);
  };

  // phase tables (stage side, unchanged from verified R2/R3 schedule)
  constexpr int SST[8] = {0,1,0,1,0,1,0,1};  // 0=A chunk, 1=B chunk
  constexpr int SHF[8] = {1,1,0,0,1,1,0,0};  // which half-tile
  constexpr int SBF[8] = {1,1,0,0,0,0,1,1};  // which buffer
  constexpr int STL[8] = {1,1,2,2,2,2,3,3};  // tile = 2i + STL

  auto stagePhase = [&](int p, int i) {
    int tl = 2 * i + STL[p];
    if (tl > G_NT - 1) tl = G_NT - 1;
    if (SST[p] == 0) stageA(SBF[p], SHF[p], tl);
    else             stageB(SBF[p], SHF[p], tl);
  };

  // ---- fragment read offsets (swizzled to match staging) ----
  const int fr = lane & 15;
  const int ko = (lane >> 4) * 8;
  const int fc = ko ^ (((fr >> 1) & 3) << 3);
  const int aO = (wm * 64 + fr) * 32 + fc;   // + buf*8192 + mi*4096 + mf*512
  const int bO = (wn * 32 + fr) * 32 + fc;   // + buf*8192 + ni*4096 + nf*512

  f32x4 acc[2][4][2][2];
#pragma unroll
  for (int a = 0; a < 2; ++a)
#pragma unroll
    for (int b = 0; b < 4; ++b)
#pragma unroll
      for (int c = 0; c < 2; ++c)
#pragma unroll
        for (int d = 0; d < 2; ++d) acc[a][b][c][d] = (f32x4)0.f;

  // ---- prologue: tile0 fully + tile1 halves 0 -> 12 loads, keep 4 in flight
  stageA(0, 0, 0); stageB(0, 0, 0);
  stageA(0, 1, 0); stageB(0, 1, 0);
  stageA(1, 0, 1); stageB(1, 0, 1);
  asm volatile("s_waitcnt vmcnt(4)" ::: "memory");   // buf0 fully landed
  __builtin_amdgcn_s_barrier();
  __builtin_amdgcn_sched_barrier(0);

  // Fragment register sets. A0/B0 also receive next-buf prefetches at q3.
  bf16x8 fah0[4], fal0[4], fah1[4], fal1[4];
  bf16x8 fbh0[2], fbl0[2], fbh1[2], fbl1[2];

  // initial reads: A0,B0 of buf0 (covered by prologue vmcnt)
#pragma unroll
  for (int mf = 0; mf < 4; ++mf) {
    fah0[mf] = *(const bf16x8*)&LAh[aO + mf * 512];
    fal0[mf] = *(const bf16x8*)&LAl[aO + mf * 512];
  }
#pragma unroll
  for (int nf = 0; nf < 2; ++nf) {
    fbh0[nf] = *(const bf16x8*)&LBh[bO + nf * 512];
    fbl0[nf] = *(const bf16x8*)&LBl[bO + nf * 512];
  }

  for (int i = 0; i < G_NT / 2; ++i) {
#pragma unroll
    for (int half = 0; half < 2; ++half) {
      const int base = half * 4;
      const int cb   = half * 8192;
      const int cbn  = cb ^ 8192;

      // ---- q0: MFMA (0,0) with A0,B0; prefetch B1 inside the MFMA window
      stagePhase(base + 0, i);
      __builtin_amdgcn_s_barrier();
      __builtin_amdgcn_sched_barrier(0);
#pragma unroll
      for (int nf = 0; nf < 2; ++nf) {
        fbh1[nf] = *(const bf16x8*)&LBh[cb + 4096 + bO + nf * 512];
        fbl1[nf] = *(const bf16x8*)&LBl[cb + 4096 + bO + nf * 512];
      }
      __builtin_amdgcn_s_setprio(1);
      MFMA_TRIPLE(0, 0, fah0, fal0, fbh0, fbl0)
      __builtin_amdgcn_s_setprio(0);
      __builtin_amdgcn_s_barrier();
      __builtin_amdgcn_sched_barrier(0);

      // ---- q1: MFMA (0,1) with A0,B1; prefetch A1
      stagePhase(base + 1, i);
      __builtin_amdgcn_s_barrier();
      __builtin_amdgcn_sched_barrier(0);
#pragma unroll
      for (int mf = 0; mf < 4; ++mf) {
        fah1[mf] = *(const bf16x8*)&LAh[cb + 4096 + aO + mf * 512];
        fal1[mf] = *(const bf16x8*)&LAl[cb + 4096 + aO + mf * 512];
      }
      __builtin_amdgcn_s_setprio(1);
      MFMA_TRIPLE(0, 1, fah0, fal0, fbh1, fbl1)
      __builtin_amdgcn_s_setprio(0);
      __builtin_amdgcn_s_barrier();
      __builtin_amdgcn_sched_barrier(0);

      // ---- q2: MFMA (1,0) with A1,B0 (no prefetch)
      stagePhase(base + 2, i);
      __builtin_amdgcn_s_barrier();
      __builtin_amdgcn_sched_barrier(0);
      __builtin_amdgcn_s_setprio(1);
      MFMA_TRIPLE(1, 0, fah1, fal1, fbh0, fbl0)
      __builtin_amdgcn_s_setprio(0);
      __builtin_amdgcn_s_barrier();
      __builtin_amdgcn_sched_barrier(0);

      // ---- q3: vmcnt gate; prefetch next-buf A0',B0' into dead A0/B0 regs;
      //          MFMA (1,1) with A1,B1
      stagePhase(base + 3, i);
      __builtin_amdgcn_s_barrier();
      __builtin_amdgcn_sched_barrier(0);
      asm volatile("s_waitcnt vmcnt(4)" ::: "memory");  // next buf fully landed
#pragma unroll
      for (int mf = 0; mf < 4; ++mf) {
        fah0[mf] = *(const bf16x8*)&LAh[cbn + aO + mf * 512];
        fal0[mf] = *(const bf16x8*)&LAl[cbn + aO + mf * 512];
      }
#pragma unroll
      for (int nf = 0; nf < 2; ++nf) {
        fbh0[nf] = *(const bf16x8*)&LBh[cbn + bO + nf * 512];
        fbl0[nf] = *(const bf16x8*)&LBl[cbn + bO + nf * 512];
      }
      __builtin_amdgcn_s_setprio(1);
      MFMA_TRIPLE(1, 1, fah1, fal1, fbh1, fbl1)
      __builtin_amdgcn_s_setprio(0);
      __builtin_amdgcn_s_barrier();
      __builtin_amdgcn_sched_barrier(0);
    }
  }
  asm volatile("s_waitcnt vmcnt(0)" ::: "memory");

  // Epilogue: bias + relu, write h split hi/lo bf16.
  // C frag layout: col=lane&15, row=(lane>>4)*4+reg
#pragma unroll
  for (int mi = 0; mi < 2; ++mi)
#pragma unroll
    for (int ni = 0; ni < 2; ++ni)
#pragma unroll
      for (int nf = 0; nf < 2; ++nf) {
        const int nn = n0 + wn * 32 + ni * 128 + nf * 16 + fr;
        const float bias = b1[nn];
#pragma unroll
        for (int mf = 0; mf < 4; ++mf) {
          const int mb = m0 + wm * 64 + mi * 128 + mf * 16 + (lane >> 4) * 4;
#pragma unroll
          for (int r = 0; r < 4; ++r) {
            const float vv = fmaxf(acc[mi][mf][ni][nf][r] + bias, 0.f);
            const unsigned short hv = bf_rne(vv);
            const float fh = __uint_as_float(((unsigned)hv) << 16);
            const unsigned short lv = bf_rne(vv - fh);
            hhp[(size_t)(mb + r) * H_DIM + nn] = hv;
            hlp[(size_t)(mb + r) * H_DIM + nn] = lv;
          }
        }
      }
}

// ---------------------------------------------------------------------------
// K1 fallback (workspace too small for xh/xl): proven 128^2 2-phase kernel.
// ---------------------------------------------------------------------------
#define BM 128
#define BN 128
#define BKK 32

__global__ __launch_bounds__(256) void gemm1_fb_kernel(
    const float* __restrict__ x,
    const unsigned short* __restrict__ w1h,
    const unsigned short* __restrict__ w1l,
    const float* __restrict__ b1,
    unsigned short* __restrict__ hhp, unsigned short* __restrict__ hlp) {
  __shared__ unsigned short Ah[BM * BKK];
  __shared__ unsigned short Al[BM * BKK];
  __shared__ unsigned short Bh[BN * BKK];
  __shared__ unsigned short Bl[BN * BKK];

  const int t    = threadIdx.x;
  const int lane = t & 63;
  const int w    = t >> 6;
  const int wm   = w >> 1;
  const int wn   = w & 1;
  const int m0   = blockIdx.y * BM;
  const int n0   = blockIdx.x * BN;

  const int e0 = (w * 2 + 0) * 512 + lane * 8;
  const int e1 = (w * 2 + 1) * 512 + lane * 8;
  const int r0 = e0 >> 5, c0 = e0 & 31;
  const int r1 = e1 >> 5, c1 = e1 & 31;
  const unsigned short* bh_g0 = w1h + (size_t)(n0 + r0) * D_DIM + c0;
  const unsigned short* bh_g1 = w1h + (size_t)(n0 + r1) * D_DIM + c1;
  const unsigned short* bl_g0 = w1l + (size_t)(n0 + r0) * D_DIM + c0;
  const unsigned short* bl_g1 = w1l + (size_t)(n0 + r1) * D_DIM + c1;
  unsigned short* bh_l0 = &Bh[e0];
  unsigned short* bh_l1 = &Bh[e1];
  unsigned short* bl_l0 = &Bl[e0];
  unsigned short* bl_l1 = &Bl[e1];

  const int ar = t >> 1;
  const int ac = (t & 1) * 16;
  const float* xp = x + (size_t)(m0 + ar) * D_DIM + ac;
  unsigned short* ah_w = &Ah[ar * BKK + ac];
  unsigned short* al_w = &Al[ar * BKK + ac];

  const int koff = (lane >> 4) * 8;
  const unsigned short* a_rd[4];
  const unsigned short* b_rd[4];
#pragma unroll
  for (int f = 0; f < 4; ++f) {
    a_rd[f] = &Ah[(wm * 64 + f * 16 + (lane & 15)) * BKK + koff];
    b_rd[f] = &Bh[(wn * 64 + f * 16 + (lane & 15)) * BKK + koff];
  }
  const int lo_off_a = (int)(Al - Ah);
  const int lo_off_b = (int)(Bl - Bh);

  f32x4 acc[4][4];
#pragma unroll
  for (int i = 0; i < 4; ++i)
#pragma unroll
    for (int j = 0; j < 4; ++j) acc[i][j] = (f32x4)0.f;

  for (int k0 = 0; k0 < D_DIM; k0 += BKK) {
    async_copy16(bh_g0 + k0, bh_l0);
    async_copy16(bh_g1 + k0, bh_l1);
    async_copy16(bl_g0 + k0, bl_l0);
    async_copy16(bl_g1 + k0, bl_l1);

    float4 v[4];
#pragma unroll
    for (int j = 0; j < 4; ++j) v[j] = *(const float4*)(xp + k0 + j * 4);
    float f[16] = {v[0].x, v[0].y, v[0].z, v[0].w, v[1].x, v[1].y, v[1].z, v[1].w,
                   v[2].x, v[2].y, v[2].z, v[2].w, v[3].x, v[3].y, v[3].z, v[3].w};
    ushort8 hv0, hv1, lv0, lv1;
#pragma unroll
    for (int j = 0; j < 8; ++j) {
      unsigned short h = bf_rne(f[j]);
      float fh = __uint_as_float(((unsigned)h) << 16);
      hv0[j] = h;
      lv0[j] = bf_rne(f[j] - fh);
    }
#pragma unroll
    for (int j = 0; j < 8; ++j) {
      unsigned short h = bf_rne(f[8 + j]);
      float fh = __uint_as_float(((unsigned)h) << 16);
      hv1[j] = h;
      lv1[j] = bf_rne(f[8 + j] - fh);
    }
    *(ushort8*)(ah_w)     = hv0;
    *(ushort8*)(ah_w + 8) = hv1;
    *(ushort8*)(al_w)     = lv0;
    *(ushort8*)(al_w + 8) = lv1;

    __syncthreads();

    bf16x8 fa_h[4], fa_l[4], fb_h[4], fb_l[4];
#pragma unroll
    for (int ff = 0; ff < 4; ++ff) {
      fa_h[ff] = *(const bf16x8*)(a_rd[ff]);
      fa_l[ff] = *(const bf16x8*)(a_rd[ff] + lo_off_a);
      fb_h[ff] = *(const bf16x8*)(b_rd[ff]);
      fb_l[ff] = *(const bf16x8*)(b_rd[ff] + lo_off_b);
    }
#pragma unroll
    for (int i = 0; i < 4; ++i)
#pragma unroll
      for (int j = 0; j < 4; ++j) {
        acc[i][j] = __builtin_amdgcn_mfma_f32_16x16x32_bf16(fa_h[i], fb_h[j], acc[i][j], 0, 0, 0);
        acc[i][j] = __builtin_amdgcn_mfma_f32_16x16x32_bf16(fa_l[i], fb_h[j], acc[i][j], 0, 0, 0);
        acc[i][j] = __builtin_amdgcn_mfma_f32_16x16x32_bf16(fa_h[i], fb_l[j], acc[i][j], 0, 0, 0);
      }
    __syncthreads();
  }

#pragma unroll
  for (int fn = 0; fn < 4; ++fn) {
    const int n = n0 + wn * 64 + fn * 16 + (lane & 15);
    const float bias = b1[n];
#pragma unroll
    for (int fm = 0; fm < 4; ++fm) {
      const int mbase = m0 + wm * 64 + fm * 16 + (lane >> 4) * 4;
#pragma unroll
      for (int r = 0; r < 4; ++r) {
        const float vv = fmaxf(acc[fm][fn][r] + bias, 0.f);
        const unsigned short hv = bf_rne(vv);
        const float fh = __uint_as_float(((unsigned)hv) << 16);
        const unsigned short lv = bf_rne(vv - fh);
        hhp[(size_t)(mbase + r) * H_DIM + n] = hv;
        hlp[(size_t)(mbase + r) * H_DIM + n] = lv;
      }
    }
  }
}

// ---------------------------------------------------------------------------
// K2 fused: double-buffered prefetch pipeline (stage t+1 -> vmcnt(8) ->
// barrier -> compute t), then top-2 + softmax + entropy. Unchanged.
// ---------------------------------------------------------------------------
#define F_BM 64
#define F_BK 64
#define F_NT (H_DIM / F_BK)   // 32

__global__ __launch_bounds__(256) void gemm2_router_kernel(
    const unsigned short* __restrict__ hhp,
    const unsigned short* __restrict__ hlp,
    const unsigned short* __restrict__ w2h,
    const unsigned short* __restrict__ w2l,
    const float* __restrict__ b2,
    float* __restrict__ out, float* __restrict__ accum) {
  __shared__ unsigned short Ahs[2 * 4096];   // [buf][64][64] bf16 = 16 KB
  __shared__ unsigned short Als[2 * 4096];
  __shared__ unsigned short Bhs[2 * 4096];
  __shared__ unsigned short Bls[2 * 4096];
  __shared__ float LG[F_BM][E_DIM + 1];

  const int t    = threadIdx.x;
  const int lane = t & 63;
  const int w    = t >> 6;
  const int m0   = blockIdx.x * F_BM;

  const int srow = w * 8 + (lane >> 3);
  const int scol = ((lane & 7) * 8) ^ (((lane >> 3) & 7) << 3);
  const int t8   = t * 8;
  const unsigned short* gAh = hhp + (size_t)(m0 + srow) * H_DIM + scol;
  const unsigned short* gAl = hlp + (size_t)(m0 + srow) * H_DIM + scol;
  const unsigned short* gBh = w2h + (size_t)srow * H_DIM + scol;
  const unsigned short* gBl = w2l + (size_t)srow * H_DIM + scol;

  auto stage2 = [&](int buf, int kt) {
    const size_t k0 = (size_t)kt * F_BK;
#pragma unroll
    for (int c = 0; c < 2; ++c) {
      const size_t go = k0 + (size_t)c * 32 * H_DIM;
      const int lo = buf * 4096 + c * 2048 + t8;
      async_copy16(gAh + go, &Ahs[lo]);
      async_copy16(gAl + go, &Als[lo]);
      async_copy16(gBh + go, &Bhs[lo]);
      async_copy16(gBl + go, &Bls[lo]);
    }
  };

  const int fr = lane & 15;
  const int ko = (lane >> 4) * 8;
  const int Ra = w * 16 + fr;
  int aoff[2], boff[2][4];
#pragma unroll
  for (int kk = 0; kk < 2; ++kk) {
    aoff[kk] = Ra * 64 + ((kk * 32 + ko) ^ ((Ra & 7) << 3));
#pragma unroll
    for (int f = 0; f < 4; ++f) {
      const int Rb = f * 16 + fr;
      boff[kk][f] = Rb * 64 + ((kk * 32 + ko) ^ ((Rb & 7) << 3));
    }
  }

  f32x4 acc[4];
#pragma unroll
  for (int f = 0; f < 4; ++f) acc[f] = (f32x4)0.f;

  stage2(0, 0);
  int buf = 0;
  for (int kt = 0; kt < F_NT; ++kt) {
    if (kt + 1 < F_NT) {
      stage2(buf ^ 1, kt + 1);
      asm volatile("s_waitcnt vmcnt(8)" ::: "memory");   // cur tile's 8 landed
    } else {
      asm volatile("s_waitcnt vmcnt(0)" ::: "memory");
    }
    __builtin_amdgcn_s_barrier();
    __builtin_amdgcn_sched_barrier(0);
    const int bo = buf * 4096;
#pragma unroll
    for (int kk = 0; kk < 2; ++kk) {
      bf16x8 fa_h = *(const bf16x8*)&Ahs[bo + aoff[kk]];
      bf16x8 fa_l = *(const bf16x8*)&Als[bo + aoff[kk]];
#pragma unroll
      for (int f = 0; f < 4; ++f) {
        bf16x8 fb_h = *(const bf16x8*)&Bhs[bo + boff[kk][f]];
        bf16x8 fb_l = *(const bf16x8*)&Bls[bo + boff[kk][f]];
        acc[f] = __builtin_amdgcn_mfma_f32_16x16x32_bf16(fa_h, fb_h, acc[f], 0, 0, 0);
        acc[f] = __builtin_amdgcn_mfma_f32_16x16x32_bf16(fa_l, fb_h, acc[f], 0, 0, 0);
        acc[f] = __builtin_amdgcn_mfma_f32_16x16x32_bf16(fa_h, fb_l, acc[f], 0, 0, 0);
      }
    }
    __builtin_amdgcn_s_barrier();
    __builtin_amdgcn_sched_barrier(0);
    buf ^= 1;
  }

  // Epilogue: bias, stash logits tile in LDS.
#pragma unroll
  for (int f = 0; f < 4; ++f) {
    const int e = f * 16 + fr;
    const float bias = b2[e];
#pragma unroll
    for (int r = 0; r < 4; ++r) {
      const int ml = w * 16 + (lane >> 4) * 4 + r;
      LG[ml][e] = acc[f][r] + bias;
    }
  }
  __syncthreads();

  // Router: threads 0..63 each own one row.
  if (t < F_BM) {
    const int row = m0 + t;
    float l0 = LG[t][0]; int i0 = 0;
    float l1 = -INFINITY; int i1 = -1;
#pragma unroll
    for (int e = 1; e < E_DIM; ++e) {
      float v = LG[t][e];
      if (v > l0)      { l1 = l0; i1 = i0; l0 = v; i0 = e; }
      else if (v > l1) { l1 = v; i1 = e; }
    }

    const float eT = expf((l1 - l0) / TEMP);
    const float w0 = 1.f / (1.f + eT);
    const float w1 = eT / (1.f + eT);

    float Z = 0.f;
#pragma unroll
    for (int e = 0; e < E_DIM; ++e) Z += expf(LG[t][e] - l0);
    const float invZ = 1.f / Z;
    float ent = 0.f;
#pragma unroll
    for (int e = 0; e < E_DIM; ++e) {
      float p = expf(LG[t][e] - l0) * invZ;
      ent -= p * logf(p + 1e-10f);
    }

    out[(size_t)row * 2 + 0] = w0;
    out[(size_t)row * 2 + 1] = w1;
    out[(size_t)B_ROWS * 2 + (size_t)row * 2 + 0] = (float)i0;
    out[(size_t)B_ROWS * 2 + (size_t)row * 2 + 1] = (float)i1;

#pragma unroll
    for (int off = 32; off > 0; off >>= 1) ent += __shfl_down(ent, off);
    if (t == 0) atomicAdd(accum, ent);
  }
}

__global__ void zero_kernel(float* p) { p[0] = 0.f; }

__global__ void finalize_kernel(const float* __restrict__ accum,
                                float* __restrict__ out) {
  out[(size_t)B_ROWS * 4] = accum[0] / ((float)B_ROWS * logf((float)E_DIM));
}

// ---------------------------------------------------------------------------
extern "C" void kernel_launch(void* const* d_in, const int* in_sizes, int n_in,
                              void* d_out, int out_size, void* d_ws,
                              size_t ws_size, hipStream_t stream) {
  const float* x  = (const float*)d_in[0];
  const float* W1 = (const float*)d_in[1];
  const float* b1 = (const float*)d_in[2];
  const float* W2 = (const float*)d_in[3];
  const float* b2 = (const float*)d_in[4];
  float* out = (float*)d_out;

  const size_t SZ_W1 = (size_t)H_DIM * D_DIM;
  const size_t SZ_W2 = (size_t)E_DIM * H_DIM;
  const size_t SZ_H  = (size_t)B_ROWS * H_DIM;
  const size_t SZ_X  = (size_t)B_ROWS * D_DIM;

  unsigned short* w1h = (unsigned short*)d_ws;
  unsigned short* w1l = w1h + SZ_W1;
  unsigned short* w2h = w1l + SZ_W1;
  unsigned short* w2l = w2h + SZ_W2;
  unsigned short* hhp = w2l + SZ_W2;
  unsigned short* hlp = hhp + SZ_H;
  float* accum        = (float*)(hlp + SZ_H);
  unsigned short* xh  = (unsigned short*)(accum + 64);
  unsigned short* xl  = xh + SZ_X;
  const size_t need_bytes = (size_t)((char*)(xl + SZ_X) - (char*)d_ws);
  const bool fast = ws_size >= need_bytes;

  zero_kernel<<<1, 1, 0, stream>>>(accum);

  split_kernel<<<(int)(SZ_W1 / (256 * 8)), 256, 0, stream>>>(W1, w1h, w1l);
  split_kernel<<<(int)(SZ_W2 / (256 * 8)), 256, 0, stream>>>(W2, w2h, w2l);

  if (fast) {
    split_kernel<<<(int)(SZ_X / (256 * 8)), 256, 0, stream>>>(x, xh, xl);
    // 1D grid + in-kernel XCD-slab mapping (512 blocks = 64 mt x 8 nt)
    gemm1_8ph_kernel<<<512, 512, 0, stream>>>(xh, xl, w1h, w1l, b1, hhp, hlp);
  } else {
    dim3 g1f(H_DIM / BN, B_ROWS / BM);     // (16, 128)
    gemm1_fb_kernel<<<g1f, 256, 0, stream>>>(x, w1h, w1l, b1, hhp, hlp);
  }

  gemm2_router_kernel<<<B_ROWS / F_BM, 256, 0, stream>>>(hhp, hlp, w2h, w2l, b2,
                                                         out, accum);

  finalize_kernel<<<1, 1, 0, stream>>>(accum, out);
}

// Round 6
// 1043.495 us; speedup vs baseline: 1.1203x; 1.1203x over previous
//
#include <hip/hip_runtime.h>
#include <hip/hip_bf16.h>
#include <math.h>

// Problem constants (fixed by the reference)
#define B_ROWS 16384
#define D_DIM  4096
#define H_DIM  2048
#define E_DIM  64
#define TEMP   0.8f

typedef __bf16 bf16x8 __attribute__((ext_vector_type(8)));
typedef float  f32x4  __attribute__((ext_vector_type(4)));
typedef unsigned short ushort8 __attribute__((ext_vector_type(8)));

__device__ __forceinline__ unsigned short bf_rne(float f) {
  unsigned u = __float_as_uint(f);
  u += 0x7FFF + ((u >> 16) & 1);
  return (unsigned short)(u >> 16);
}

__device__ __forceinline__ void async_copy16(const void* g, void* l) {
  __builtin_amdgcn_global_load_lds(
      (const __attribute__((address_space(1))) void*)g,
      (__attribute__((address_space(3))) void*)l, 16, 0, 0);
}

// ---------------------------------------------------------------------------
// split: fp32 -> (hi bf16, lo bf16), RNE both. 8 elements / thread.
// ---------------------------------------------------------------------------
__global__ __launch_bounds__(256) void split_kernel(
    const float* __restrict__ in, unsigned short* __restrict__ hi,
    unsigned short* __restrict__ lo) {
  const size_t i = ((size_t)blockIdx.x * 256 + threadIdx.x) * 8;
  float4 v0 = *(const float4*)(in + i);
  float4 v1 = *(const float4*)(in + i + 4);
  float f[8] = {v0.x, v0.y, v0.z, v0.w, v1.x, v1.y, v1.z, v1.w};
  ushort8 hv, lv;
#pragma unroll
  for (int j = 0; j < 8; ++j) {
    unsigned short h = bf_rne(f[j]);
    float fh = __uint_as_float(((unsigned)h) << 16);
    hv[j] = h;
    lv[j] = bf_rne(f[j] - fh);
  }
  *(ushort8*)(hi + i) = hv;
  *(ushort8*)(lo + i) = lv;
}

// ---------------------------------------------------------------------------
// K1 v7: main loop = EXACT R4 structure (676 us proven: 8-phase counted-vmcnt,
// XCD-slab mapping, register-hoisted fragment reads in the stage window).
// R5's prefetch-shift REVERTED (spill evidence: WRITE_SIZE 142->398 MB).
// NEW fused epilogue: per-block partial logits GEMM (split-K over h-cols):
//   h tile (256x256, bias+relu, split hi/lo) -> staging LDS (XOR-swizzled,
//   2 passes of 128 rows) -> MFMA vs W2 frags read direct from global ->
//   logitsP[nt][16384][64] fp32 (no atomics; deterministic partial order).
// Eliminates: h write (134 MB), h read (134 MB), the entire gemm2 kernel.
// ---------------------------------------------------------------------------
#define G_BM 256
#define G_BN 256
#define G_BK 32
#define G_NT (D_DIM / G_BK)   // 128 K-tiles, 64 iters

#define MFMA_TRIPLE(MIv, NIv, FAH, FAL, FBH, FBL)                               \
  _Pragma("unroll")                                                             \
  for (int mf = 0; mf < 4; ++mf) {                                              \
    _Pragma("unroll")                                                           \
    for (int nf = 0; nf < 2; ++nf) {                                            \
      f32x4 a = acc[MIv][mf][NIv][nf];                                          \
      a = __builtin_amdgcn_mfma_f32_16x16x32_bf16(FAH[mf], FBH[nf], a, 0, 0, 0);\
      a = __builtin_amdgcn_mfma_f32_16x16x32_bf16(FAL[mf], FBH[nf], a, 0, 0, 0);\
      a = __builtin_amdgcn_mfma_f32_16x16x32_bf16(FAH[mf], FBL[nf], a, 0, 0, 0);\
      acc[MIv][mf][NIv][nf] = a;                                                \
    }                                                                           \
  }

__global__ __launch_bounds__(512, 2) void gemm1_8ph_kernel(
    const unsigned short* __restrict__ xh, const unsigned short* __restrict__ xl,
    const unsigned short* __restrict__ w1h, const unsigned short* __restrict__ w1l,
    const float* __restrict__ b1,
    const unsigned short* __restrict__ w2h, const unsigned short* __restrict__ w2l,
    float* __restrict__ logitsP) {
  __shared__ unsigned short SMEM[65536];   // 128 KB, staging + epilogue reuse
  unsigned short* const LAh = SMEM;            // [buf][256][32] = 16384 ush
  unsigned short* const LAl = SMEM + 16384;
  unsigned short* const LBh = SMEM + 32768;
  unsigned short* const LBl = SMEM + 49152;

  const int t    = threadIdx.x;          // 0..511
  const int lane = t & 63;
  const int w    = t >> 6;               // 0..7
  const int wm   = w >> 2;               // 0..1
  const int wn   = w & 3;                // 0..3

  // XCD-slab swizzle (bijective: 512 wgs = 8 xcds x 8 mt x 8 nt)
  const int wg   = blockIdx.x;
  const int xcd  = wg & 7;
  const int slot = wg >> 3;              // 0..63
  const int mt   = xcd * 8 + (slot >> 3);
  const int nt   = slot & 7;
  const int m0   = mt * G_BM;
  const int n0   = nt * G_BN;

  // ---- staging addresses: 512 threads cover 128 rows x 4 col-chunks ----
  const int sr  = t >> 2;                        // 0..127
  const int sc  = (t & 3) * 8;
  const int scs = sc ^ (((sr >> 1) & 3) << 3);   // pre-swizzled source col
  const int t8  = t * 8;                         // linear dest
  const unsigned short* gAh = xh  + (size_t)(m0 + sr) * D_DIM + scs;
  const unsigned short* gAl = xl  + (size_t)(m0 + sr) * D_DIM + scs;
  const unsigned short* gBh = w1h + (size_t)(n0 + sr) * D_DIM + scs;
  const unsigned short* gBl = w1l + (size_t)(n0 + sr) * D_DIM + scs;

  auto stageA = [&](int buf, int half, int kt) {
    const size_t go = (size_t)half * 128 * D_DIM + (size_t)kt * G_BK;
    const int lo = buf * 8192 + half * 4096 + t8;
    async_copy16(gAh + go, &LAh[lo]);
    async_copy16(gAl + go, &LAl[lo]);
  };
  auto stageB = [&](int buf, int half, int kt) {
    const size_t go = (size_t)half * 128 * D_DIM + (size_t)kt * G_BK;
    const int lo = buf * 8192 + half * 4096 + t8;
    async_copy16(gBh + go, &LBh[lo]);
    async_copy16(gBl + go, &LBl[lo]);
  };

  // phase tables (stage side, verified R2/R3/R4 schedule)
  constexpr int SST[8] = {0,1,0,1,0,1,0,1};  // 0=A chunk, 1=B chunk
  constexpr int SHF[8] = {1,1,0,0,1,1,0,0};  // which half-tile
  constexpr int SBF[8] = {1,1,0,0,0,0,1,1};  // which buffer
  constexpr int STL[8] = {1,1,2,2,2,2,3,3};  // tile = 2i + STL

  auto stagePhase = [&](int p, int i) {
    int tl = 2 * i + STL[p];
    if (tl > G_NT - 1) tl = G_NT - 1;
    if (SST[p] == 0) stageA(SBF[p], SHF[p], tl);
    else             stageB(SBF[p], SHF[p], tl);
  };

  // ---- fragment read offsets (swizzled to match staging) ----
  const int fr = lane & 15;
  const int ko = (lane >> 4) * 8;
  const int fc = ko ^ (((fr >> 1) & 3) << 3);
  const int aO = (wm * 64 + fr) * 32 + fc;   // + buf*8192 + mi*4096 + mf*512
  const int bO = (wn * 32 + fr) * 32 + fc;   // + buf*8192 + ni*4096 + nf*512

  f32x4 acc[2][4][2][2];
#pragma unroll
  for (int a = 0; a < 2; ++a)
#pragma unroll
    for (int b = 0; b < 4; ++b)
#pragma unroll
      for (int c = 0; c < 2; ++c)
#pragma unroll
        for (int d = 0; d < 2; ++d) acc[a][b][c][d] = (f32x4)0.f;

  // ---- prologue: tile0 fully + tile1 halves 0 -> 12 loads, keep 4 in flight
  stageA(0, 0, 0); stageB(0, 0, 0);
  stageA(0, 1, 0); stageB(0, 1, 0);
  stageA(1, 0, 1); stageB(1, 0, 1);
  asm volatile("s_waitcnt vmcnt(4)" ::: "memory");
  __builtin_amdgcn_s_barrier();
  __builtin_amdgcn_sched_barrier(0);

  for (int i = 0; i < G_NT / 2; ++i) {
#pragma unroll
    for (int half = 0; half < 2; ++half) {
      const int base = half * 4;        // global phase p = base + q
      const int cb   = half * 8192;

      bf16x8 fah[4], fal[4];            // current A set (overwritten at q=2)
      bf16x8 fbh0[2], fbl0[2];          // B set NI=0 (held through q=2)
      bf16x8 fbh1[2], fbl1[2];          // B set NI=1 (held through q=3)

      // ---- q=0: read A(MI=0) + B(NI=0); mfma quadrant (0,0)
#pragma unroll
      for (int mf = 0; mf < 4; ++mf) {
        fah[mf] = *(const bf16x8*)&LAh[cb + aO + mf * 512];
        fal[mf] = *(const bf16x8*)&LAl[cb + aO + mf * 512];
      }
#pragma unroll
      for (int nf = 0; nf < 2; ++nf) {
        fbh0[nf] = *(const bf16x8*)&LBh[cb + bO + nf * 512];
        fbl0[nf] = *(const bf16x8*)&LBl[cb + bO + nf * 512];
      }
      stagePhase(base + 0, i);
      __builtin_amdgcn_s_barrier();
      __builtin_amdgcn_sched_barrier(0);
      __builtin_amdgcn_s_setprio(1);
      MFMA_TRIPLE(0, 0, fah, fal, fbh0, fbl0)
      __builtin_amdgcn_s_setprio(0);
      __builtin_amdgcn_s_barrier();
      __builtin_amdgcn_sched_barrier(0);

      // ---- q=1: read B(NI=1); mfma quadrant (0,1)
#pragma unroll
      for (int nf = 0; nf < 2; ++nf) {
        fbh1[nf] = *(const bf16x8*)&LBh[cb + 4096 + bO + nf * 512];
        fbl1[nf] = *(const bf16x8*)&LBl[cb + 4096 + bO + nf * 512];
      }
      stagePhase(base + 1, i);
      __builtin_amdgcn_s_barrier();
      __builtin_amdgcn_sched_barrier(0);
      __builtin_amdgcn_s_setprio(1);
      MFMA_TRIPLE(0, 1, fah, fal, fbh1, fbl1)
      __builtin_amdgcn_s_setprio(0);
      __builtin_amdgcn_s_barrier();
      __builtin_amdgcn_sched_barrier(0);

      // ---- q=2: read A(MI=1); mfma quadrant (1,0) with held B0
#pragma unroll
      for (int mf = 0; mf < 4; ++mf) {
        fah[mf] = *(const bf16x8*)&LAh[cb + 4096 + aO + mf * 512];
        fal[mf] = *(const bf16x8*)&LAl[cb + 4096 + aO + mf * 512];
      }
      stagePhase(base + 2, i);
      __builtin_amdgcn_s_barrier();
      __builtin_amdgcn_sched_barrier(0);
      __builtin_amdgcn_s_setprio(1);
      MFMA_TRIPLE(1, 0, fah, fal, fbh0, fbl0)
      __builtin_amdgcn_s_setprio(0);
      __builtin_amdgcn_s_barrier();
      __builtin_amdgcn_sched_barrier(0);

      // ---- q=3: no reads; mfma quadrant (1,1) with held A1,B1
      stagePhase(base + 3, i);
      __builtin_amdgcn_s_barrier();
      __builtin_amdgcn_sched_barrier(0);
      __builtin_amdgcn_s_setprio(1);
      MFMA_TRIPLE(1, 1, fah, fal, fbh1, fbl1)
      __builtin_amdgcn_s_setprio(0);
      asm volatile("s_waitcnt vmcnt(4)" ::: "memory");
      __builtin_amdgcn_s_barrier();
      __builtin_amdgcn_sched_barrier(0);
    }
  }
  asm volatile("s_waitcnt vmcnt(0)" ::: "memory");
  __syncthreads();   // staging reads all done; LDS is free for epilogue reuse

  // =========================================================================
  // Fused epilogue: partial logits for this block's 256 h-cols.
  //   logitsP[nt][row][e] = sum_{k in [n0,n0+256)} h[row][k]*W2[e][k]
  // h hi/lo values identical to the old h-write path (bias+relu+bf_rne).
  // LDS: Hh = SMEM[0..32768), Hl = SMEM[32768..65536)  (128 rows x 256 cols)
  // Swizzle: elem (r,c) at r*256 + ((u ^ (r&7))<<3) + (c&7), u = c>>3.
  // 2 passes over mi (128 rows each).
  // =========================================================================
  unsigned short* const Hh = SMEM;
  unsigned short* const Hl = SMEM + 32768;

#pragma unroll
  for (int mi = 0; mi < 2; ++mi) {
    // ---- write pass: split h into LDS
#pragma unroll
    for (int ni = 0; ni < 2; ++ni)
#pragma unroll
      for (int nf = 0; nf < 2; ++nf) {
        const int colb = wn * 32 + ni * 128 + nf * 16 + fr;
        const float bias = b1[n0 + colb];
        const int u = colb >> 3, j = colb & 7;
#pragma unroll
        for (int mf = 0; mf < 4; ++mf) {
          const int rowb = wm * 64 + mf * 16 + (lane >> 4) * 4;
#pragma unroll
          for (int r = 0; r < 4; ++r) {
            const int rr = rowb + r;
            const float vv = fmaxf(acc[mi][mf][ni][nf][r] + bias, 0.f);
            const unsigned short hv = bf_rne(vv);
            const float fh = __uint_as_float(((unsigned)hv) << 16);
            const unsigned short lv = bf_rne(vv - fh);
            const int a = rr * 256 + ((u ^ (rr & 7)) << 3) + j;
            Hh[a] = hv;
            Hl[a] = lv;
          }
        }
      }
    __syncthreads();

    // ---- compute pass: wave w owns rows [w*16, w*16+16) of this 128-slice
    f32x4 lac[4];
#pragma unroll
    for (int nf = 0; nf < 4; ++nf) lac[nf] = (f32x4)0.f;

    const int arow = w * 16 + fr;     // A-frag row (lane&15 = row)
#pragma unroll
    for (int kf = 0; kf < 8; ++kf) {
      const int au = (kf * 4 + (lane >> 4)) ^ (arow & 7);
      bf16x8 ahi = *(const bf16x8*)&Hh[arow * 256 + au * 8];
      bf16x8 alo = *(const bf16x8*)&Hl[arow * 256 + au * 8];
#pragma unroll
      for (int nf = 0; nf < 4; ++nf) {
        const size_t boff = (size_t)(nf * 16 + fr) * H_DIM + n0 + kf * 32 + ko;
        bf16x8 bhi = *(const bf16x8*)(w2h + boff);
        bf16x8 blo = *(const bf16x8*)(w2l + boff);
        lac[nf] = __builtin_amdgcn_mfma_f32_16x16x32_bf16(ahi, bhi, lac[nf], 0, 0, 0);
        lac[nf] = __builtin_amdgcn_mfma_f32_16x16x32_bf16(alo, bhi, lac[nf], 0, 0, 0);
        lac[nf] = __builtin_amdgcn_mfma_f32_16x16x32_bf16(ahi, blo, lac[nf], 0, 0, 0);
      }
    }

    // ---- store partials: C layout col(e)=lane&15, row=(lane>>4)*4+r
    float* lpb = logitsP + (size_t)nt * ((size_t)B_ROWS * E_DIM);
#pragma unroll
    for (int nf = 0; nf < 4; ++nf) {
      const int e = nf * 16 + fr;
#pragma unroll
      for (int r = 0; r < 4; ++r) {
        const int grow = m0 + mi * 128 + w * 16 + (lane >> 4) * 4 + r;
        lpb[(size_t)grow * E_DIM + e] = lac[nf][r];
      }
    }
    __syncthreads();   // before next pass overwrites LDS
  }
}

// ---------------------------------------------------------------------------
// Router: sum 8 partials + b2 -> top-2 + softmax weights + entropy.
// One thread per row; 64 blocks x 256 threads.
// ---------------------------------------------------------------------------
__global__ __launch_bounds__(256) void router_kernel(
    const float* __restrict__ lp, const float* __restrict__ b2,
    float* __restrict__ out, float* __restrict__ accum) {
  const int t = threadIdx.x;
  const size_t row = (size_t)blockIdx.x * 256 + t;
  const size_t PS = (size_t)B_ROWS * E_DIM;

  float lg[64];
#pragma unroll
  for (int e4 = 0; e4 < 16; ++e4) {
    float4 v = *(const float4*)(lp + row * E_DIM + e4 * 4);
    lg[e4 * 4 + 0] = v.x; lg[e4 * 4 + 1] = v.y;
    lg[e4 * 4 + 2] = v.z; lg[e4 * 4 + 3] = v.w;
  }
#pragma unroll
  for (int p = 1; p < 8; ++p) {
#pragma unroll
    for (int e4 = 0; e4 < 16; ++e4) {
      float4 v = *(const float4*)(lp + (size_t)p * PS + row * E_DIM + e4 * 4);
      lg[e4 * 4 + 0] += v.x; lg[e4 * 4 + 1] += v.y;
      lg[e4 * 4 + 2] += v.z; lg[e4 * 4 + 3] += v.w;
    }
  }
#pragma unroll
  for (int e = 0; e < E_DIM; ++e) lg[e] += b2[e];

  float l0 = lg[0]; int i0 = 0;
  float l1 = -INFINITY; int i1 = -1;
#pragma unroll
  for (int e = 1; e < E_DIM; ++e) {
    float v = lg[e];
    if (v > l0)      { l1 = l0; i1 = i0; l0 = v; i0 = e; }
    else if (v > l1) { l1 = v; i1 = e; }
  }

  const float eT = expf((l1 - l0) / TEMP);
  const float w0 = 1.f / (1.f + eT);
  const float w1 = eT / (1.f + eT);

  float Z = 0.f;
#pragma unroll
  for (int e = 0; e < E_DIM; ++e) Z += expf(lg[e] - l0);
  const float invZ = 1.f / Z;
  float ent = 0.f;
#pragma unroll
  for (int e = 0; e < E_DIM; ++e) {
    float p = expf(lg[e] - l0) * invZ;
    ent -= p * logf(p + 1e-10f);
  }

  out[row * 2 + 0] = w0;
  out[row * 2 + 1] = w1;
  out[(size_t)B_ROWS * 2 + row * 2 + 0] = (float)i0;
  out[(size_t)B_ROWS * 2 + row * 2 + 1] = (float)i1;

#pragma unroll
  for (int off = 32; off > 0; off >>= 1) ent += __shfl_down(ent, off);
  if ((t & 63) == 0) atomicAdd(accum, ent);
}

// ---------------------------------------------------------------------------
// K1 fallback (workspace too small for xh/xl): proven 128^2 2-phase kernel,
// writes split h; paired with the old gemm2 router below.
// ---------------------------------------------------------------------------
#define BM 128
#define BN 128
#define BKK 32

__global__ __launch_bounds__(256) void gemm1_fb_kernel(
    const float* __restrict__ x,
    const unsigned short* __restrict__ w1h,
    const unsigned short* __restrict__ w1l,
    const float* __restrict__ b1,
    unsigned short* __restrict__ hhp, unsigned short* __restrict__ hlp) {
  __shared__ unsigned short Ah[BM * BKK];
  __shared__ unsigned short Al[BM * BKK];
  __shared__ unsigned short Bh[BN * BKK];
  __shared__ unsigned short Bl[BN * BKK];

  const int t    = threadIdx.x;
  const int lane = t & 63;
  const int w    = t >> 6;
  const int wm   = w >> 1;
  const int wn   = w & 1;
  const int m0   = blockIdx.y * BM;
  const int n0   = blockIdx.x * BN;

  const int e0 = (w * 2 + 0) * 512 + lane * 8;
  const int e1 = (w * 2 + 1) * 512 + lane * 8;
  const int r0 = e0 >> 5, c0 = e0 & 31;
  const int r1 = e1 >> 5, c1 = e1 & 31;
  const unsigned short* bh_g0 = w1h + (size_t)(n0 + r0) * D_DIM + c0;
  const unsigned short* bh_g1 = w1h + (size_t)(n0 + r1) * D_DIM + c1;
  const unsigned short* bl_g0 = w1l + (size_t)(n0 + r0) * D_DIM + c0;
  const unsigned short* bl_g1 = w1l + (size_t)(n0 + r1) * D_DIM + c1;
  unsigned short* bh_l0 = &Bh[e0];
  unsigned short* bh_l1 = &Bh[e1];
  unsigned short* bl_l0 = &Bl[e0];
  unsigned short* bl_l1 = &Bl[e1];

  const int ar = t >> 1;
  const int ac = (t & 1) * 16;
  const float* xp = x + (size_t)(m0 + ar) * D_DIM + ac;
  unsigned short* ah_w = &Ah[ar * BKK + ac];
  unsigned short* al_w = &Al[ar * BKK + ac];

  const int koff = (lane >> 4) * 8;
  const unsigned short* a_rd[4];
  const unsigned short* b_rd[4];
#pragma unroll
  for (int f = 0; f < 4; ++f) {
    a_rd[f] = &Ah[(wm * 64 + f * 16 + (lane & 15)) * BKK + koff];
    b_rd[f] = &Bh[(wn * 64 + f * 16 + (lane & 15)) * BKK + koff];
  }
  const int lo_off_a = (int)(Al - Ah);
  const int lo_off_b = (int)(Bl - Bh);

  f32x4 acc[4][4];
#pragma unroll
  for (int i = 0; i < 4; ++i)
#pragma unroll
    for (int j = 0; j < 4; ++j) acc[i][j] = (f32x4)0.f;

  for (int k0 = 0; k0 < D_DIM; k0 += BKK) {
    async_copy16(bh_g0 + k0, bh_l0);
    async_copy16(bh_g1 + k0, bh_l1);
    async_copy16(bl_g0 + k0, bl_l0);
    async_copy16(bl_g1 + k0, bl_l1);

    float4 v[4];
#pragma unroll
    for (int j = 0; j < 4; ++j) v[j] = *(const float4*)(xp + k0 + j * 4);
    float f[16] = {v[0].x, v[0].y, v[0].z, v[0].w, v[1].x, v[1].y, v[1].z, v[1].w,
                   v[2].x, v[2].y, v[2].z, v[2].w, v[3].x, v[3].y, v[3].z, v[3].w};
    ushort8 hv0, hv1, lv0, lv1;
#pragma unroll
    for (int j = 0; j < 8; ++j) {
      unsigned short h = bf_rne(f[j]);
      float fh = __uint_as_float(((unsigned)h) << 16);
      hv0[j] = h;
      lv0[j] = bf_rne(f[j] - fh);
    }
#pragma unroll
    for (int j = 0; j < 8; ++j) {
      unsigned short h = bf_rne(f[8 + j]);
      float fh = __uint_as_float(((unsigned)h) << 16);
      hv1[j] = h;
      lv1[j] = bf_rne(f[8 + j] - fh);
    }
    *(ushort8*)(ah_w)     = hv0;
    *(ushort8*)(ah_w + 8) = hv1;
    *(ushort8*)(al_w)     = lv0;
    *(ushort8*)(al_w + 8) = lv1;

    __syncthreads();

    bf16x8 fa_h[4], fa_l[4], fb_h[4], fb_l[4];
#pragma unroll
    for (int ff = 0; ff < 4; ++ff) {
      fa_h[ff] = *(const bf16x8*)(a_rd[ff]);
      fa_l[ff] = *(const bf16x8*)(a_rd[ff] + lo_off_a);
      fb_h[ff] = *(const bf16x8*)(b_rd[ff]);
      fb_l[ff] = *(const bf16x8*)(b_rd[ff] + lo_off_b);
    }
#pragma unroll
    for (int i = 0; i < 4; ++i)
#pragma unroll
      for (int j = 0; j < 4; ++j) {
        acc[i][j] = __builtin_amdgcn_mfma_f32_16x16x32_bf16(fa_h[i], fb_h[j], acc[i][j], 0, 0, 0);
        acc[i][j] = __builtin_amdgcn_mfma_f32_16x16x32_bf16(fa_l[i], fb_h[j], acc[i][j], 0, 0, 0);
        acc[i][j] = __builtin_amdgcn_mfma_f32_16x16x32_bf16(fa_h[i], fb_l[j], acc[i][j], 0, 0, 0);
      }
    __syncthreads();
  }

#pragma unroll
  for (int fn = 0; fn < 4; ++fn) {
    const int n = n0 + wn * 64 + fn * 16 + (lane & 15);
    const float bias = b1[n];
#pragma unroll
    for (int fm = 0; fm < 4; ++fm) {
      const int mbase = m0 + wm * 64 + fm * 16 + (lane >> 4) * 4;
#pragma unroll
      for (int r = 0; r < 4; ++r) {
        const float vv = fmaxf(acc[fm][fn][r] + bias, 0.f);
        const unsigned short hv = bf_rne(vv);
        const float fh = __uint_as_float(((unsigned)hv) << 16);
        const unsigned short lv = bf_rne(vv - fh);
        hhp[(size_t)(mbase + r) * H_DIM + n] = hv;
        hlp[(size_t)(mbase + r) * H_DIM + n] = lv;
      }
    }
  }
}

// ---------------------------------------------------------------------------
// Fallback gemm2 (unchanged R2-proven): used only when workspace is small.
// ---------------------------------------------------------------------------
#define F_BM 64
#define F_BK 64
#define F_NT (H_DIM / F_BK)   // 32

__global__ __launch_bounds__(256) void gemm2_router_kernel(
    const unsigned short* __restrict__ hhp,
    const unsigned short* __restrict__ hlp,
    const unsigned short* __restrict__ w2h,
    const unsigned short* __restrict__ w2l,
    const float* __restrict__ b2,
    float* __restrict__ out, float* __restrict__ accum) {
  __shared__ unsigned short Ahs[2 * 4096];
  __shared__ unsigned short Als[2 * 4096];
  __shared__ unsigned short Bhs[2 * 4096];
  __shared__ unsigned short Bls[2 * 4096];
  __shared__ float LG[F_BM][E_DIM + 1];

  const int t    = threadIdx.x;
  const int lane = t & 63;
  const int w    = t >> 6;
  const int m0   = blockIdx.x * F_BM;

  const int srow = w * 8 + (lane >> 3);
  const int scol = ((lane & 7) * 8) ^ (((lane >> 3) & 7) << 3);
  const int t8   = t * 8;
  const unsigned short* gAh = hhp + (size_t)(m0 + srow) * H_DIM + scol;
  const unsigned short* gAl = hlp + (size_t)(m0 + srow) * H_DIM + scol;
  const unsigned short* gBh = w2h + (size_t)srow * H_DIM + scol;
  const unsigned short* gBl = w2l + (size_t)srow * H_DIM + scol;

  auto stage2 = [&](int buf, int kt) {
    const size_t k0 = (size_t)kt * F_BK;
#pragma unroll
    for (int c = 0; c < 2; ++c) {
      const size_t go = k0 + (size_t)c * 32 * H_DIM;
      const int lo = buf * 4096 + c * 2048 + t8;
      async_copy16(gAh + go, &Ahs[lo]);
      async_copy16(gAl + go, &Als[lo]);
      async_copy16(gBh + go, &Bhs[lo]);
      async_copy16(gBl + go, &Bls[lo]);
    }
  };

  const int fr = lane & 15;
  const int ko = (lane >> 4) * 8;
  const int Ra = w * 16 + fr;
  int aoff[2], boff[2][4];
#pragma unroll
  for (int kk = 0; kk < 2; ++kk) {
    aoff[kk] = Ra * 64 + ((kk * 32 + ko) ^ ((Ra & 7) << 3));
#pragma unroll
    for (int f = 0; f < 4; ++f) {
      const int Rb = f * 16 + fr;
      boff[kk][f] = Rb * 64 + ((kk * 32 + ko) ^ ((Rb & 7) << 3));
    }
  }

  f32x4 acc[4];
#pragma unroll
  for (int f = 0; f < 4; ++f) acc[f] = (f32x4)0.f;

  stage2(0, 0);
  int buf = 0;
  for (int kt = 0; kt < F_NT; ++kt) {
    if (kt + 1 < F_NT) {
      stage2(buf ^ 1, kt + 1);
      asm volatile("s_waitcnt vmcnt(8)" ::: "memory");
    } else {
      asm volatile("s_waitcnt vmcnt(0)" ::: "memory");
    }
    __builtin_amdgcn_s_barrier();
    __builtin_amdgcn_sched_barrier(0);
    const int bo = buf * 4096;
#pragma unroll
    for (int kk = 0; kk < 2; ++kk) {
      bf16x8 fa_h = *(const bf16x8*)&Ahs[bo + aoff[kk]];
      bf16x8 fa_l = *(const bf16x8*)&Als[bo + aoff[kk]];
#pragma unroll
      for (int f = 0; f < 4; ++f) {
        bf16x8 fb_h = *(const bf16x8*)&Bhs[bo + boff[kk][f]];
        bf16x8 fb_l = *(const bf16x8*)&Bls[bo + boff[kk][f]];
        acc[f] = __builtin_amdgcn_mfma_f32_16x16x32_bf16(fa_h, fb_h, acc[f], 0, 0, 0);
        acc[f] = __builtin_amdgcn_mfma_f32_16x16x32_bf16(fa_l, fb_h, acc[f], 0, 0, 0);
        acc[f] = __builtin_amdgcn_mfma_f32_16x16x32_bf16(fa_h, fb_l, acc[f], 0, 0, 0);
      }
    }
    __builtin_amdgcn_s_barrier();
    __builtin_amdgcn_sched_barrier(0);
    buf ^= 1;
  }

#pragma unroll
  for (int f = 0; f < 4; ++f) {
    const int e = f * 16 + fr;
    const float bias = b2[e];
#pragma unroll
    for (int r = 0; r < 4; ++r) {
      const int ml = w * 16 + (lane >> 4) * 4 + r;
      LG[ml][e] = acc[f][r] + bias;
    }
  }
  __syncthreads();

  if (t < F_BM) {
    const int row = m0 + t;
    float l0 = LG[t][0]; int i0 = 0;
    float l1 = -INFINITY; int i1 = -1;
#pragma unroll
    for (int e = 1; e < E_DIM; ++e) {
      float v = LG[t][e];
      if (v > l0)      { l1 = l0; i1 = i0; l0 = v; i0 = e; }
      else if (v > l1) { l1 = v; i1 = e; }
    }

    const float eT = expf((l1 - l0) / TEMP);
    const float w0 = 1.f / (1.f + eT);
    const float w1 = eT / (1.f + eT);

    float Z = 0.f;
#pragma unroll
    for (int e = 0; e < E_DIM; ++e) Z += expf(LG[t][e] - l0);
    const float invZ = 1.f / Z;
    float ent = 0.f;
#pragma unroll
    for (int e = 0; e < E_DIM; ++e) {
      float p = expf(LG[t][e] - l0) * invZ;
      ent -= p * logf(p + 1e-10f);
    }

    out[(size_t)row * 2 + 0] = w0;
    out[(size_t)row * 2 + 1] = w1;
    out[(size_t)B_ROWS * 2 + (size_t)row * 2 + 0] = (float)i0;
    out[(size_t)B_ROWS * 2 + (size_t)row * 2 + 1] = (float)i1;

#pragma unroll
    for (int off = 32; off > 0; off >>= 1) ent += __shfl_down(ent, off);
    if (t == 0) atomicAdd(accum, ent);
  }
}

__global__ void zero_kernel(float* p) { p[0] = 0.f; }

__global__ void finalize_kernel(const float* __restrict__ accum,
                                float* __restrict__ out) {
  out[(size_t)B_ROWS * 4] = accum[0] / ((float)B_ROWS * logf((float)E_DIM));
}

// ---------------------------------------------------------------------------
extern "C" void kernel_launch(void* const* d_in, const int* in_sizes, int n_in,
                              void* d_out, int out_size, void* d_ws,
                              size_t ws_size, hipStream_t stream) {
  const float* x  = (const float*)d_in[0];
  const float* W1 = (const float*)d_in[1];
  const float* b1 = (const float*)d_in[2];
  const float* W2 = (const float*)d_in[3];
  const float* b2 = (const float*)d_in[4];
  float* out = (float*)d_out;

  const size_t SZ_W1 = (size_t)H_DIM * D_DIM;
  const size_t SZ_W2 = (size_t)E_DIM * H_DIM;
  const size_t SZ_H  = (size_t)B_ROWS * H_DIM;
  const size_t SZ_X  = (size_t)B_ROWS * D_DIM;

  unsigned short* w1h = (unsigned short*)d_ws;
  unsigned short* w1l = w1h + SZ_W1;
  unsigned short* w2h = w1l + SZ_W1;
  unsigned short* w2l = w2h + SZ_W2;
  // union region: fast path -> logitsP (8 x 16384 x 64 fp32 = 33.5 MB);
  //               fallback  -> hhp/hlp (134 MB). Sized for the larger.
  unsigned short* hhp = w2l + SZ_W2;
  unsigned short* hlp = hhp + SZ_H;
  float* logitsP      = (float*)hhp;
  float* accum        = (float*)(hlp + SZ_H);
  unsigned short* xh  = (unsigned short*)(accum + 64);
  unsigned short* xl  = xh + SZ_X;
  const size_t need_bytes = (size_t)((char*)(xl + SZ_X) - (char*)d_ws);
  const bool fast = ws_size >= need_bytes;

  zero_kernel<<<1, 1, 0, stream>>>(accum);

  split_kernel<<<(int)(SZ_W1 / (256 * 8)), 256, 0, stream>>>(W1, w1h, w1l);
  split_kernel<<<(int)(SZ_W2 / (256 * 8)), 256, 0, stream>>>(W2, w2h, w2l);

  if (fast) {
    split_kernel<<<(int)(SZ_X / (256 * 8)), 256, 0, stream>>>(x, xh, xl);
    // 1D grid + in-kernel XCD-slab mapping (512 blocks = 64 mt x 8 nt);
    // fused epilogue writes split-K partial logits (no h round-trip).
    gemm1_8ph_kernel<<<512, 512, 0, stream>>>(xh, xl, w1h, w1l, b1,
                                              w2h, w2l, logitsP);
    router_kernel<<<B_ROWS / 256, 256, 0, stream>>>(logitsP, b2, out, accum);
  } else {
    dim3 g1f(H_DIM / BN, B_ROWS / BM);     // (16, 128)
    gemm1_fb_kernel<<<g1f, 256, 0, stream>>>(x, w1h, w1l, b1, hhp, hlp);
    gemm2_router_kernel<<<B_ROWS / F_BM, 256, 0, stream>>>(hhp, hlp, w2h, w2l,
                                                           b2, out, accum);
  }

  finalize_kernel<<<1, 1, 0, stream>>>(accum, out);
}